// Round 9
// baseline (292.956 us; speedup 1.0000x reference)
//
#include <hip/hip_runtime.h>

typedef __attribute__((ext_vector_type(8))) short short8;
typedef __attribute__((ext_vector_type(4))) float f32x4;

#define HP 66  // padded spatial dim

__device__ __forceinline__ unsigned short f2bf(float f) {
  unsigned u = __builtin_bit_cast(unsigned, f);
  u += 0x7FFFu + ((u >> 16) & 1u);
  return (unsigned short)(u >> 16);
}
__device__ __forceinline__ float bf2f(unsigned short h) {
  return __builtin_bit_cast(float, ((unsigned)h) << 16);
}
__device__ __forceinline__ __attribute__((address_space(3))) void* to_as3(void* p) {
  return (__attribute__((address_space(3))) void*)(unsigned)(unsigned long long)p;
}
__device__ __forceinline__ const __attribute__((address_space(1))) void* to_as1(const void* p) {
  return (const __attribute__((address_space(1))) void*)(unsigned long long)p;
}

#define SB0() __builtin_amdgcn_sched_barrier(0)
#define BAR() do { SB0(); __builtin_amdgcn_s_barrier(); SB0(); } while (0)

// ---------------- K0: zero the halo ring of the padded NHWC buffer ----------------
__global__ void k_halo_zero(unsigned int* xp) {
  int p = blockIdx.x % 260;
  int b = blockIdx.x / 260;
  int h, w;
  if (p < 66)      { h = 0;  w = p; }
  else if (p < 132){ h = 65; w = p - 66; }
  else             { int q = p - 132; h = 1 + (q >> 1); w = (q & 1) * 65; }
  unsigned int* dst = xp + ((long)((b*HP + h)*HP + w) * 256) / 2;
  dst[threadIdx.x] = 0u;
  dst[threadIdx.x + 64] = 0u;
}

// ---------------- K1: x NCHW f32 -> padded NHWC bf16 (LDS transpose) ----------------
__global__ __launch_bounds__(256) void k_convert_x(const float* __restrict__ x,
                                                   unsigned short* __restrict__ xp) {
  __shared__ float tile[32][65];
  int blk = blockIdx.x;
  int ct = blk & 7, h = (blk >> 3) & 63, b = blk >> 9;
  int c0 = ct * 32;
  int t = threadIdx.x;
  int w = t & 63, cs = t >> 6;
#pragma unroll
  for (int i = 0; i < 8; ++i) {
    int c = cs + i * 4;
    tile[c][w] = x[(((b * 256) + c0 + c) * 64 + h) * 64 + w];
  }
  __syncthreads();
  int cl = (t & 15) * 2, w0 = t >> 4;
#pragma unroll
  for (int i = 0; i < 4; ++i) {
    int ww = w0 + i * 16;
    unsigned v = (unsigned)f2bf(tile[cl][ww]) | ((unsigned)f2bf(tile[cl + 1][ww]) << 16);
    *(unsigned*)(xp + ((long)((b*HP + h + 1)*HP + (ww + 1)) * 256 + c0 + cl)) = v;
  }
}

// ---------------- K1b: pack both conv weights [O][I][3][3] f32 -> Wt[co][kk*256+ci] bf16 ----------------
__global__ void k_pack_w(const float* __restrict__ w1, const float* __restrict__ w2,
                         unsigned short* __restrict__ wT1, unsigned short* __restrict__ wT2) {
  const float* w = blockIdx.y ? w2 : w1;
  unsigned short* wT = blockIdx.y ? wT2 : wT1;
  int co = blockIdx.x;
  int t = threadIdx.x;  // = ci
#pragma unroll
  for (int kk = 0; kk < 9; ++kk) {
    wT[co * 2304 + kk * 256 + t] = f2bf(w[(co * 256 + t) * 9 + kk]);
  }
}

// ---------------- K2: both gates = softmax(emb @ gw + gb) ----------------
__global__ __launch_bounds__(256) void k_gates(const float* __restrict__ emb,
                                               const float* __restrict__ g1w,
                                               const float* __restrict__ g1b,
                                               const float* __restrict__ g2w,
                                               const float* __restrict__ g2b,
                                               float* __restrict__ gate1,
                                               float* __restrict__ gate2) {
  const float* gw = blockIdx.y ? g2w : g1w;
  const float* gbias = blockIdx.y ? g2b : g1b;
  float* gout = blockIdx.y ? gate2 : gate1;
  __shared__ float ebuf[512];
  __shared__ float red[8];
  int b = blockIdx.x, t = threadIdx.x;
  ebuf[t] = emb[b * 512 + t];
  ebuf[t + 256] = emb[b * 512 + t + 256];
  __syncthreads();
  float acc = gbias[t];
  for (int k = 0; k < 512; ++k) acc += ebuf[k] * gw[k * 256 + t];
  float mx = acc;
  for (int off = 32; off >= 1; off >>= 1) mx = fmaxf(mx, __shfl_xor(mx, off));
  if ((t & 63) == 0) red[t >> 6] = mx;
  __syncthreads();
  mx = fmaxf(fmaxf(red[0], red[1]), fmaxf(red[2], red[3]));
  float e = expf(acc - mx);
  float sm = e;
  for (int off = 32; off >= 1; off >>= 1) sm += __shfl_xor(sm, off);
  if ((t & 63) == 0) red[4 + (t >> 6)] = sm;
  __syncthreads();
  sm = red[4] + red[5] + red[6] + red[7];
  gout[b * 256 + t] = e / sm;
}

// ---------------- K3/K6: implicit-GEMM 3x3 conv, 256x256 tile ----------------
// A staged in LDS (dbuf, swizzled); B read DIRECT from global (L2-resident weights) into
// double-buffered register fragments with one-kt lookahead.
// inp: padded NHWC bf16 [16][66][66][256]; wT: [256][2304]; gate: [16][256]
// yout: [65536][256] bf16; partials: [256 blk][256 c][2] f32
__global__ __launch_bounds__(512, 2) void k_conv(
    const unsigned short* __restrict__ inp,
    const unsigned short* __restrict__ wT,
    const float* __restrict__ gate,
    unsigned short* __restrict__ yout,
    float* __restrict__ partials) {
  __shared__ short As[2][256][64];   // 64 KB (XOR-swizzled: chunk ^= row&7)
  __shared__ float sbuf[2][256][2];  // 4 KB epilogue reduce

  const int t = threadIdx.x;
  const int lane = t & 63;
  const int wid = t >> 6;            // 0..7
  const int wm = wid >> 2;           // 0..1  (M half)
  const int wn = wid & 3;            // 0..3  (N quarter)
  const int lr = lane & 15;
  const int hi = lane >> 4;
  const int key = lr & 7;            // read-side swizzle key (A only)

  // XCD-aware bijective swizzle: each XCD (8 total) owns 32 consecutive blocks = 2 whole images
  const int blk = ((blockIdx.x & 7) << 5) + (blockIdx.x >> 3);   // 0..255
  const int b = blk >> 4;
  const int hh4 = (blk & 15) << 2;

  // staging geometry: thread stages rows {r0, r0+64} of a 128-row half, 16B chunk
  const int r0 = t >> 3;             // 0..63
  const int cdst = (t & 7) << 3;     // dest element offset (linear LDS)
  const int cg8 = (((t & 7) ^ ((t >> 3) & 7)) << 3);  // pre-swizzled source offset

  int aoff[4];
#pragma unroll
  for (int i = 0; i < 4; ++i)
    aoff[i] = (b * HP + hh4 + i) * HP + r0;

  auto stageA = [&](int buf, int half, int s) {
    int kk = s >> 2;
    int kh = (kk * 11) >> 5;          // kk/3 for kk<=8
    int khw = kh * 66 + (kk - kh * 3);
    int ci = ((s & 3) << 6) + cg8;
    const unsigned short* g0 = inp + (long)(aoff[half * 2 + 0] + khw) * 256 + ci;
    const unsigned short* g1 = inp + (long)(aoff[half * 2 + 1] + khw) * 256 + ci;
    __builtin_amdgcn_global_load_lds(to_as1(g0), to_as3((void*)&As[buf][half * 128 + r0][cdst]), 16, 0, 0);
    __builtin_amdgcn_global_load_lds(to_as1(g1), to_as3((void*)&As[buf][half * 128 + 64 + r0][cdst]), 16, 0, 0);
  };

  // per-thread B base: co = wn*64 + nf*16 + lr ; k-offset = ks*32 + hi*8 (+ kt*64)
  const unsigned short* wTq = wT + (long)(wn * 64 + lr) * 2304 + hi * 8;

  f32x4 acc[8][4];
#pragma unroll
  for (int i = 0; i < 8; ++i)
#pragma unroll
    for (int j = 0; j < 4; ++j) acc[i][j] = (f32x4){0.f, 0.f, 0.f, 0.f};

  short8 afrag[4][2];                // one A m-half at a time (refilled twice per kt)
  short8 bfA[4][2], bfB[4][2];       // B double-buffer (global-loaded, one-kt lookahead)

#define LD_B(BF, kt)                                                                 \
  _Pragma("unroll") for (int nf = 0; nf < 4; ++nf)                                   \
    _Pragma("unroll") for (int ks = 0; ks < 2; ++ks)                                 \
      BF[nf][ks] = *(const short8*)(wTq + (long)nf * 16 * 2304 + (kt) * 64 + ks * 32);

#define RD_A(MH, BUF)                                                                \
  _Pragma("unroll") for (int mf = 0; mf < 4; ++mf)                                   \
    _Pragma("unroll") for (int ks = 0; ks < 2; ++ks)                                 \
      afrag[mf][ks] = *(const short8*)&As[BUF][wm * 128 + ((MH) * 4 + mf) * 16 + lr][((ks * 4 + hi) ^ key) << 3];

#define QUADN(BF, mh, nh)                                                            \
  do {                                                                               \
    __builtin_amdgcn_s_setprio(1);                                                   \
    _Pragma("unroll") for (int ks = 0; ks < 2; ++ks)                                 \
      _Pragma("unroll") for (int mo = 0; mo < 4; ++mo)                               \
        _Pragma("unroll") for (int no = 0; no < 2; ++no)                             \
          acc[(mh) * 4 + mo][(nh) * 2 + no] = __builtin_amdgcn_mfma_f32_16x16x32_bf16( \
              afrag[mo][ks], BF[(nh) * 2 + no][ks],                                  \
              acc[(mh) * 4 + mo][(nh) * 2 + no], 0, 0, 0);                           \
    __builtin_amdgcn_s_setprio(0);                                                   \
  } while (0)

  // ---- prologue: stage A tiles 0,1; load B(0) direct ----
  stageA(0, 0, 0); stageA(0, 1, 0);    // 4 ops
  stageA(1, 0, 1); stageA(1, 1, 1);    // 4 ops
  LD_B(bfA, 0);                        // 8 ops
  asm volatile("s_waitcnt vmcnt(0)" ::: "memory");
  BAR();
  RD_A(0, 0);                          // afrag = A0(tile0)

  // steady kt body. P1: issue B(kt+1) loads; 64 MFMA with afrag refill mid-way.
  // P2: stage A(kt+2); vmcnt(12) certifies A(kt+1); read A0(kt+1); vmcnt(4) certifies B(kt+1).
#define KT_STEADY(SEL, kt, BC, BN_)                                                  \
  {                                                                                  \
    LD_B(BN_, (kt) + 1);                                                             \
    SB0();                                                                           \
    QUADN(BC, 0, 0);                                                                 \
    QUADN(BC, 0, 1);                                                                 \
    RD_A(1, SEL);                                                                    \
    QUADN(BC, 1, 0);                                                                 \
    QUADN(BC, 1, 1);                                                                 \
    BAR();                                                                           \
    stageA(SEL, 0, (kt) + 2); stageA(SEL, 1, (kt) + 2);                              \
    asm volatile("s_waitcnt vmcnt(12)" ::: "memory");                                \
    RD_A(0, SEL ^ 1);                                                                \
    asm volatile("s_waitcnt vmcnt(4)" ::: "memory");                                 \
    BAR();                                                                           \
  }

  for (int i = 0; i < 17; ++i) {
    const int kt0 = 2 * i;
    KT_STEADY(0, kt0, bfA, bfB)
    KT_STEADY(1, kt0 + 1, bfB, bfA)
  }
  // kt=34 (SEL=0, BC=bfA): load B(35); no stage
  {
    LD_B(bfB, 35);
    SB0();
    QUADN(bfA, 0, 0);
    QUADN(bfA, 0, 1);
    RD_A(1, 0);
    QUADN(bfA, 1, 0);
    QUADN(bfA, 1, 1);
    BAR();
    asm volatile("s_waitcnt vmcnt(8)" ::: "memory");   // A(35) landed
    RD_A(0, 1);
    asm volatile("s_waitcnt vmcnt(0)" ::: "memory");   // B(35) landed
    BAR();
  }
  // kt=35 (BC=bfB)
  {
    QUADN(bfB, 0, 0);
    QUADN(bfB, 0, 1);
    RD_A(1, 1);
    QUADN(bfB, 1, 0);
    QUADN(bfB, 1, 1);
  }
#undef KT_STEADY
#undef QUADN
#undef RD_A
#undef LD_B

  // ---- epilogue: gate, bf16 store, per-channel {sum,sumsq} partials ----
  float g[4];
#pragma unroll
  for (int nf = 0; nf < 4; ++nf) g[nf] = gate[(b << 8) + wn * 64 + nf * 16 + lr];

  float s[4] = {0, 0, 0, 0}, sq[4] = {0, 0, 0, 0};
  const int mrow0 = (blk << 8) + wm * 128 + (hi << 2);
  const int c0 = wn * 64 + lr;
#pragma unroll
  for (int mf = 0; mf < 8; ++mf)
#pragma unroll
    for (int r = 0; r < 4; ++r) {
      const int mm = mrow0 + mf * 16 + r;
#pragma unroll
      for (int nf = 0; nf < 4; ++nf) {
        float v = acc[mf][nf][r] * g[nf];
        yout[(long)mm * 256 + c0 + nf * 16] = f2bf(v);
        s[nf] += v;
        sq[nf] += v * v;
      }
    }
#pragma unroll
  for (int nf = 0; nf < 4; ++nf) {
    s[nf] += __shfl_xor(s[nf], 16);  s[nf] += __shfl_xor(s[nf], 32);
    sq[nf] += __shfl_xor(sq[nf], 16); sq[nf] += __shfl_xor(sq[nf], 32);
  }
  __syncthreads();
  if (hi == 0) {
#pragma unroll
    for (int nf = 0; nf < 4; ++nf) {
      int c = wn * 64 + nf * 16 + lr;
      sbuf[wm][c][0] = s[nf];
      sbuf[wm][c][1] = sq[nf];
    }
  }
  __syncthreads();
  if (t < 256) {
    partials[((blk << 8) + t) * 2]     = sbuf[0][t][0] + sbuf[1][t][0];
    partials[((blk << 8) + t) * 2 + 1] = sbuf[0][t][1] + sbuf[1][t][1];
  }
}

// ---------------- K4/K7: reduce partials -> per-channel BN affine (a, b) ----------------
__global__ __launch_bounds__(256) void k_bnfin(const float* __restrict__ partials,
                                               const float* __restrict__ gamma,
                                               const float* __restrict__ beta,
                                               float2* __restrict__ aff) {
  __shared__ float red[8];
  int c = blockIdx.x, t = threadIdx.x;
  float s = partials[(t * 256 + c) * 2];
  float sq = partials[(t * 256 + c) * 2 + 1];
  for (int off = 32; off >= 1; off >>= 1) { s += __shfl_xor(s, off); sq += __shfl_xor(sq, off); }
  if ((t & 63) == 0) { red[t >> 6] = s; red[4 + (t >> 6)] = sq; }
  __syncthreads();
  if (t == 0) {
    s = red[0] + red[1] + red[2] + red[3];
    sq = red[4] + red[5] + red[6] + red[7];
    float mean = s * (1.0f / 65536.0f);
    float var = fmaxf(sq * (1.0f / 65536.0f) - mean * mean, 0.0f);
    float inv = rsqrtf(var + 1e-5f);
    float ga = gamma[c] * inv;
    aff[c] = make_float2(ga, beta[c] - mean * ga);
  }
}

// ---------------- K5: z1 = relu(bn1(y1)) -> padded NHWC bf16 (conv2 input) ----------------
__global__ __launch_bounds__(256) void k_mid(const unsigned short* __restrict__ y1,
                                             const float2* __restrict__ aff,
                                             unsigned short* __restrict__ zp) {
  long idx = (long)blockIdx.x * 256 + threadIdx.x;
  int c0 = (int)(idx & 31) * 8;
  long pos = idx >> 5;
  int b = (int)(pos >> 12), hw = (int)(pos & 4095);
  int h = hw >> 6, w = hw & 63;
  uint4 v = *(const uint4*)(y1 + pos * 256 + c0);
  unsigned vv[4] = {v.x, v.y, v.z, v.w};
  unsigned outp[4];
#pragma unroll
  for (int j = 0; j < 4; ++j) {
    float2 aL = aff[c0 + 2 * j], aH = aff[c0 + 2 * j + 1];
    float lo = fmaxf(aL.x * bf2f((unsigned short)(vv[j] & 0xFFFF)) + aL.y, 0.f);
    float hiv = fmaxf(aH.x * bf2f((unsigned short)(vv[j] >> 16)) + aH.y, 0.f);
    outp[j] = (unsigned)f2bf(lo) | ((unsigned)f2bf(hiv) << 16);
  }
  unsigned short* dst = zp + (long)((b * HP + h + 1) * HP + w + 1) * 256 + c0;
  *(uint4*)dst = make_uint4(outp[0], outp[1], outp[2], outp[3]);
}

// ---------------- K8: out = relu(bn2(y2) + x), NHWC -> NCHW ----------------
__global__ __launch_bounds__(256) void k_final(const unsigned short* __restrict__ y2,
                                               const float2* __restrict__ aff,
                                               const float* __restrict__ x,
                                               float* __restrict__ out) {
  __shared__ float tile[64][33];
  int blk = blockIdx.x;
  int ct = blk & 7, h = (blk >> 3) & 63, b = blk >> 9;
  int c0 = ct * 32;
  int t = threadIdx.x;
  int cl = (t & 15) * 2, w0 = t >> 4;
#pragma unroll
  for (int i = 0; i < 4; ++i) {
    int w = w0 + i * 16;
    unsigned v = *(const unsigned*)(y2 + (long)((b * 4096) + h * 64 + w) * 256 + c0 + cl);
    float2 aL = aff[c0 + cl], aH = aff[c0 + cl + 1];
    tile[w][cl] = aL.x * bf2f((unsigned short)(v & 0xFFFF)) + aL.y;
    tile[w][cl + 1] = aH.x * bf2f((unsigned short)(v >> 16)) + aH.y;
  }
  __syncthreads();
  int w = t & 63, csub = t >> 6;
#pragma unroll
  for (int j = 0; j < 8; ++j) {
    int c = c0 + csub * 8 + j;
    long o = ((long)(b * 256 + c) * 64 + h) * 64 + w;
    out[o] = fmaxf(tile[w][csub * 8 + j] + x[o], 0.f);
  }
}

// ---------------- launch ----------------
extern "C" void kernel_launch(void* const* d_in, const int* in_sizes, int n_in,
                              void* d_out, int out_size, void* d_ws, size_t ws_size,
                              hipStream_t stream) {
  const float* x    = (const float*)d_in[0];
  const float* emb  = (const float*)d_in[1];
  const float* w1   = (const float*)d_in[2];
  const float* w2   = (const float*)d_in[3];
  const float* g1w  = (const float*)d_in[4];
  const float* g1b  = (const float*)d_in[5];
  const float* g2w  = (const float*)d_in[6];
  const float* g2b  = (const float*)d_in[7];
  const float* bn1g = (const float*)d_in[8];
  const float* bn1b = (const float*)d_in[9];
  const float* bn2g = (const float*)d_in[10];
  const float* bn2b = (const float*)d_in[11];

  float* out = (float*)d_out;
  float* gate1 = out + 16777216;
  float* gate2 = gate1 + 4096;

  char* ws = (char*)d_ws;
  const size_t OFF_XP  = 0;                       // 16*66*66*256*2 = 35,684,352
  const size_t OFF_WT1 = 35684352;                // 1,179,648
  const size_t OFF_WT2 = OFF_WT1 + 1179648;
  const size_t OFF_Y   = OFF_WT2 + 1179648;       // 65536*256*2 = 33,554,432
  const size_t OFF_PART = OFF_Y + 33554432;       // 524,288 used
  const size_t OFF_AFF1 = OFF_PART + 1048576;
  const size_t OFF_AFF2 = OFF_AFF1 + 2048;

  unsigned short* xp  = (unsigned short*)(ws + OFF_XP);   // reused as z1 padded
  unsigned short* wT1 = (unsigned short*)(ws + OFF_WT1);
  unsigned short* wT2 = (unsigned short*)(ws + OFF_WT2);
  unsigned short* y   = (unsigned short*)(ws + OFF_Y);
  float* part = (float*)(ws + OFF_PART);
  float2* aff1 = (float2*)(ws + OFF_AFF1);
  float2* aff2 = (float2*)(ws + OFF_AFF2);

  k_halo_zero<<<16 * 260, 64, 0, stream>>>((unsigned int*)xp);
  k_convert_x<<<8192, 256, 0, stream>>>(x, xp);
  k_pack_w<<<dim3(256, 2), 256, 0, stream>>>(w1, w2, wT1, wT2);
  k_gates<<<dim3(16, 2), 256, 0, stream>>>(emb, g1w, g1b, g2w, g2b, gate1, gate2);

  k_conv<<<256, 512, 0, stream>>>(xp, wT1, gate1, y, part);
  k_bnfin<<<256, 256, 0, stream>>>(part, bn1g, bn1b, aff1);
  k_mid<<<8192, 256, 0, stream>>>(y, aff1, xp);

  k_conv<<<256, 512, 0, stream>>>(xp, wT2, gate2, y, part);
  k_bnfin<<<256, 256, 0, stream>>>(part, bn2g, bn2b, aff2);
  k_final<<<8192, 256, 0, stream>>>(y, aff2, x, out);
}

// Round 11
// 247.831 us; speedup vs baseline: 1.1821x; 1.1821x over previous
//
#include <hip/hip_runtime.h>

typedef __attribute__((ext_vector_type(8))) short short8;
typedef __attribute__((ext_vector_type(4))) float f32x4;

#define HP 66  // padded spatial dim

__device__ __forceinline__ unsigned short f2bf(float f) {
  unsigned u = __builtin_bit_cast(unsigned, f);
  u += 0x7FFFu + ((u >> 16) & 1u);
  return (unsigned short)(u >> 16);
}
__device__ __forceinline__ float bf2f(unsigned short h) {
  return __builtin_bit_cast(float, ((unsigned)h) << 16);
}
__device__ __forceinline__ __attribute__((address_space(3))) void* to_as3(void* p) {
  return (__attribute__((address_space(3))) void*)(unsigned)(unsigned long long)p;
}
__device__ __forceinline__ const __attribute__((address_space(1))) void* to_as1(const void* p) {
  return (const __attribute__((address_space(1))) void*)(unsigned long long)p;
}

#define SB0() __builtin_amdgcn_sched_barrier(0)
#define BAR() do { SB0(); __builtin_amdgcn_s_barrier(); SB0(); } while (0)

// ---------------- K_prep: convert_x + halo_zero + pack_w + gates in ONE launch ----------------
// blocks [0,8192): x NCHW f32 -> padded NHWC bf16 (LDS transpose)
// blocks [8192,10272): zero halo ring (2080 blocks x 256 uints)
// blocks [10272,10784): pack both conv weights
// blocks [10784,10816): both gates softmax
__global__ __launch_bounds__(256) void k_prep(
    const float* __restrict__ x, unsigned short* __restrict__ xp,
    const float* __restrict__ w1, const float* __restrict__ w2,
    unsigned short* __restrict__ wT1, unsigned short* __restrict__ wT2,
    const float* __restrict__ emb,
    const float* __restrict__ g1w, const float* __restrict__ g1b,
    const float* __restrict__ g2w, const float* __restrict__ g2b,
    float* __restrict__ gate1, float* __restrict__ gate2) {
  __shared__ float tile[32][65];
  __shared__ float ebuf[512];
  __shared__ float red[8];
  const int blk = blockIdx.x;
  const int t = threadIdx.x;

  if (blk < 8192) {
    int ct = blk & 7, h = (blk >> 3) & 63, b = blk >> 9;
    int c0 = ct * 32;
    int w = t & 63, cs = t >> 6;
#pragma unroll
    for (int i = 0; i < 8; ++i) {
      int c = cs + i * 4;
      tile[c][w] = x[(((b * 256) + c0 + c) * 64 + h) * 64 + w];
    }
    __syncthreads();
    int cl = (t & 15) * 2, w0 = t >> 4;
#pragma unroll
    for (int i = 0; i < 4; ++i) {
      int ww = w0 + i * 16;
      unsigned v = (unsigned)f2bf(tile[cl][ww]) | ((unsigned)f2bf(tile[cl + 1][ww]) << 16);
      *(unsigned*)(xp + ((long)((b*HP + h + 1)*HP + (ww + 1)) * 256 + c0 + cl)) = v;
    }
  } else if (blk < 10272) {
    unsigned u = (unsigned)(blk - 8192) * 256 + t;   // < 532480
    unsigned p_idx = u >> 7, word = u & 127;
    int img = p_idx / 260, p = p_idx % 260;
    int h, w;
    if (p < 66)      { h = 0;  w = p; }
    else if (p < 132){ h = 65; w = p - 66; }
    else             { int q = p - 132; h = 1 + (q >> 1); w = (q & 1) * 65; }
    ((unsigned*)xp)[((long)((img*HP + h)*HP + w) * 256) / 2 + word] = 0u;
  } else if (blk < 10784) {
    int idx = blk - 10272;
    const float* w = (idx >> 8) ? w2 : w1;
    unsigned short* wT = (idx >> 8) ? wT2 : wT1;
    int co = idx & 255;
#pragma unroll
    for (int kk = 0; kk < 9; ++kk)
      wT[co * 2304 + kk * 256 + t] = f2bf(w[(co * 256 + t) * 9 + kk]);
  } else {
    int idx = blk - 10784;
    int b = idx & 15;
    const float* gw = (idx >> 4) ? g2w : g1w;
    const float* gbias = (idx >> 4) ? g2b : g1b;
    float* gout = (idx >> 4) ? gate2 : gate1;
    ebuf[t] = emb[b * 512 + t];
    ebuf[t + 256] = emb[b * 512 + t + 256];
    __syncthreads();
    float acc = gbias[t];
    for (int k = 0; k < 512; ++k) acc += ebuf[k] * gw[k * 256 + t];
    float mx = acc;
    for (int off = 32; off >= 1; off >>= 1) mx = fmaxf(mx, __shfl_xor(mx, off));
    if ((t & 63) == 0) red[t >> 6] = mx;
    __syncthreads();
    mx = fmaxf(fmaxf(red[0], red[1]), fmaxf(red[2], red[3]));
    float e = expf(acc - mx);
    float sm = e;
    for (int off = 32; off >= 1; off >>= 1) sm += __shfl_xor(sm, off);
    if ((t & 63) == 0) red[4 + (t >> 6)] = sm;
    __syncthreads();
    sm = red[4] + red[5] + red[6] + red[7];
    gout[b * 256 + t] = e / sm;
  }
}

// ---------------- K3/K6: implicit-GEMM 3x3 conv, 256x256 tile, 8-wave, 2-phase/kt overlap ----------------
// inp: padded NHWC bf16 [16][66][66][256]; wT: [256][2304]; gate: [16][256]
// yout: [65536][256] bf16; partials: [256 blk][256 c][2] f32
__global__ __launch_bounds__(512, 2) void k_conv(
    const unsigned short* __restrict__ inp,
    const unsigned short* __restrict__ wT,
    const float* __restrict__ gate,
    unsigned short* __restrict__ yout,
    float* __restrict__ partials) {
  __shared__ __align__(16) char pool[135168];
  auto As = reinterpret_cast<short(*)[256][64]>(pool);            // [2][256][64] = 64 KB
  auto Bs = reinterpret_cast<short(*)[256][64]>(pool + 65536);    // [2][256][64] = 64 KB
  auto sbuf = reinterpret_cast<float(*)[256][2]>(pool + 131072);  // [2][256][2] = 4 KB

  const int t = threadIdx.x;
  const int lane = t & 63;
  const int wid = t >> 6;            // 0..7
  const int wm = wid >> 2;           // 0..1  (M half)
  const int wn = wid & 3;            // 0..3  (N quarter)
  const int lr = lane & 15;
  const int hi = lane >> 4;
  const int key = lr & 7;            // read-side swizzle key

  // XCD-aware bijective swizzle: each XCD (8 total) owns 32 consecutive blocks = 2 whole images
  const int blk = ((blockIdx.x & 7) << 5) + (blockIdx.x >> 3);   // 0..255
  const int b = blk >> 4;
  const int hh4 = (blk & 15) << 2;

  // staging geometry: thread stages rows {r0, r0+64} of a 128-row half, 16B chunk
  const int r0 = t >> 3;             // 0..63
  const int cdst = (t & 7) << 3;     // dest element offset (linear LDS)
  const int cg8 = (((t & 7) ^ ((t >> 3) & 7)) << 3);  // pre-swizzled source offset

  int aoff[4];
#pragma unroll
  for (int i = 0; i < 4; ++i)
    aoff[i] = (b * HP + hh4 + i) * HP + r0;

  auto stageA = [&](int buf, int half, int s) {
    int kk = s >> 2;
    int kh = (kk * 11) >> 5;          // kk/3 for kk<=8
    int khw = kh * 66 + (kk - kh * 3);
    int ci = ((s & 3) << 6) + cg8;
    const unsigned short* g0 = inp + (long)(aoff[half * 2 + 0] + khw) * 256 + ci;
    const unsigned short* g1 = inp + (long)(aoff[half * 2 + 1] + khw) * 256 + ci;
    __builtin_amdgcn_global_load_lds(to_as1(g0), to_as3((void*)&As[buf][half * 128 + r0][cdst]), 16, 0, 0);
    __builtin_amdgcn_global_load_lds(to_as1(g1), to_as3((void*)&As[buf][half * 128 + 64 + r0][cdst]), 16, 0, 0);
  };
  auto stageB = [&](int buf, int half, int s) {
    int co0 = half * 128 + r0;
    const unsigned short* g0 = wT + (long)co0 * 2304 + s * 64 + cg8;
    const unsigned short* g1 = wT + (long)(co0 + 64) * 2304 + s * 64 + cg8;
    __builtin_amdgcn_global_load_lds(to_as1(g0), to_as3((void*)&Bs[buf][half * 128 + r0][cdst]), 16, 0, 0);
    __builtin_amdgcn_global_load_lds(to_as1(g1), to_as3((void*)&Bs[buf][half * 128 + 64 + r0][cdst]), 16, 0, 0);
  };

  f32x4 acc[8][4];
#pragma unroll
  for (int i = 0; i < 8; ++i)
#pragma unroll
    for (int j = 0; j < 4; ++j) acc[i][j] = (f32x4){0.f, 0.f, 0.f, 0.f};

  short8 afrag0[4][2], afrag1[4][2];
  short8 bfrag0[2][2], bfrag1[2][2];

#define RD_A(ARR, MH, BUF)                                                           \
  _Pragma("unroll") for (int mf = 0; mf < 4; ++mf)                                   \
    _Pragma("unroll") for (int ks = 0; ks < 2; ++ks)                                 \
      ARR[mf][ks] = *(const short8*)&As[BUF][wm * 128 + ((MH) * 4 + mf) * 16 + lr][((ks * 4 + hi) ^ key) << 3];
#define RD_B(ARR, NH, BUF)                                                           \
  _Pragma("unroll") for (int nf = 0; nf < 2; ++nf)                                   \
    _Pragma("unroll") for (int ks = 0; ks < 2; ++ks)                                 \
      ARR[nf][ks] = *(const short8*)&Bs[BUF][wn * 64 + ((NH) * 2 + nf) * 16 + lr][((ks * 4 + hi) ^ key) << 3];

#define QUADQ(AF, BF, mh, nh)                                                        \
  do {                                                                               \
    __builtin_amdgcn_s_setprio(1);                                                   \
    _Pragma("unroll") for (int ks = 0; ks < 2; ++ks)                                 \
      _Pragma("unroll") for (int mo = 0; mo < 4; ++mo)                               \
        _Pragma("unroll") for (int no = 0; no < 2; ++no)                             \
          acc[(mh) * 4 + mo][(nh) * 2 + no] = __builtin_amdgcn_mfma_f32_16x16x32_bf16( \
              AF[mo][ks], BF[no][ks], acc[(mh) * 4 + mo][(nh) * 2 + no], 0, 0, 0);   \
    __builtin_amdgcn_s_setprio(0);                                                   \
  } while (0)

  // ---- prologue: stage T0,T1 in steady-state FIFO order {B1, A0, B0, A1} ----
  stageB(0, 1, 0); stageA(0, 0, 0); stageB(0, 0, 0); stageA(0, 1, 0);
  stageB(1, 1, 1); stageA(1, 0, 1); stageB(1, 0, 1); stageA(1, 1, 1);
  asm volatile("s_waitcnt vmcnt(8)" ::: "memory");   // all of tile0 landed
  BAR();
  RD_B(bfrag0, 0, 0);
  RD_A(afrag0, 0, 0);

  // 2-phase kt body, literal buffer SEL.
#define KTHALF2(SEL, kt)                                                             \
  {                                                                                  \
    RD_B(bfrag1, 1, SEL);                                                            \
    RD_A(afrag1, 1, SEL);                                                            \
    if ((kt) + 2 < 36) stageB(SEL, 1, (kt) + 2);                                     \
    SB0();                                                                           \
    QUADQ(afrag0, bfrag0, 0, 0);                                                     \
    QUADQ(afrag0, bfrag1, 0, 1);                                                     \
    QUADQ(afrag1, bfrag0, 1, 0);                                                     \
    if ((kt) < 34) { asm volatile("s_waitcnt vmcnt(4)" ::: "memory"); }              \
    else           { asm volatile("s_waitcnt vmcnt(2)" ::: "memory"); }              \
    BAR();                                                                           \
    if ((kt) < 35) { RD_B(bfrag0, 0, SEL ^ 1); RD_A(afrag0, 0, SEL ^ 1); }           \
    if ((kt) + 2 < 36) { stageA(SEL, 0, (kt) + 2); stageB(SEL, 0, (kt) + 2); stageA(SEL, 1, (kt) + 2); } \
    SB0();                                                                           \
    QUADQ(afrag1, bfrag1, 1, 1);                                                     \
    if ((kt) < 34) { asm volatile("s_waitcnt vmcnt(8)" ::: "memory"); }              \
    else           { asm volatile("s_waitcnt vmcnt(0)" ::: "memory"); }              \
    BAR();                                                                           \
  }

  for (int i = 0; i < 18; ++i) {
    const int kt0 = 2 * i;
    KTHALF2(0, kt0)
    KTHALF2(1, kt0 + 1)
  }
#undef KTHALF2
#undef QUADQ
#undef RD_A
#undef RD_B

  // ---- epilogue: gate, LDS-bounce coalesced bf16 store, per-channel {sum,sumsq} partials ----
  float g[4];
#pragma unroll
  for (int nf = 0; nf < 4; ++nf) g[nf] = gate[(b << 8) + wn * 64 + nf * 16 + lr];

  // LZ reuses As/Bs space (dead after final BAR of the K-loop); sbuf (131072+) untouched
  auto LZ = reinterpret_cast<unsigned short(*)[256]>(pool);   // [256][256] bf16 = 128 KB
  float s[4] = {0, 0, 0, 0}, sq[4] = {0, 0, 0, 0};
#pragma unroll
  for (int mf = 0; mf < 8; ++mf) {
    const int rowb = wm * 128 + mf * 16 + (hi << 2);
#pragma unroll
    for (int r = 0; r < 4; ++r) {
#pragma unroll
      for (int nf = 0; nf < 4; ++nf) {
        float v = acc[mf][nf][r] * g[nf];
        LZ[rowb + r][wn * 64 + nf * 16 + lr] = f2bf(v);
        s[nf] += v;
        sq[nf] += v * v;
      }
    }
  }
#pragma unroll
  for (int nf = 0; nf < 4; ++nf) {
    s[nf] += __shfl_xor(s[nf], 16);  s[nf] += __shfl_xor(s[nf], 32);
    sq[nf] += __shfl_xor(sq[nf], 16); sq[nf] += __shfl_xor(sq[nf], 32);
  }
  if (hi == 0) {
#pragma unroll
    for (int nf = 0; nf < 4; ++nf) {
      int c = wn * 64 + nf * 16 + lr;
      sbuf[wm][c][0] = s[nf];
      sbuf[wm][c][1] = sq[nf];
    }
  }
  __syncthreads();
  // coalesced y store: each 32-lane group writes one full 512B row chunk-contiguous
#pragma unroll
  for (int it = 0; it < 16; ++it) {
    const int row = it * 16 + (t >> 5);
    *(uint4*)(yout + (long)(blk * 256 + row) * 256 + (t & 31) * 8) =
        *(const uint4*)&LZ[row][(t & 31) * 8];
  }
  if (t < 256) {
    partials[((blk << 8) + t) * 2]     = sbuf[0][t][0] + sbuf[1][t][0];
    partials[((blk << 8) + t) * 2 + 1] = sbuf[0][t][1] + sbuf[1][t][1];
  }
}

// ---------------- K4/K7: reduce partials -> per-channel BN affine (a, b) ----------------
__global__ __launch_bounds__(256) void k_bnfin(const float* __restrict__ partials,
                                               const float* __restrict__ gamma,
                                               const float* __restrict__ beta,
                                               float2* __restrict__ aff) {
  __shared__ float red[8];
  int c = blockIdx.x, t = threadIdx.x;
  float s = partials[(t * 256 + c) * 2];
  float sq = partials[(t * 256 + c) * 2 + 1];
  for (int off = 32; off >= 1; off >>= 1) { s += __shfl_xor(s, off); sq += __shfl_xor(sq, off); }
  if ((t & 63) == 0) { red[t >> 6] = s; red[4 + (t >> 6)] = sq; }
  __syncthreads();
  if (t == 0) {
    s = red[0] + red[1] + red[2] + red[3];
    sq = red[4] + red[5] + red[6] + red[7];
    float mean = s * (1.0f / 65536.0f);
    float var = fmaxf(sq * (1.0f / 65536.0f) - mean * mean, 0.0f);
    float inv = rsqrtf(var + 1e-5f);
    float ga = gamma[c] * inv;
    aff[c] = make_float2(ga, beta[c] - mean * ga);
  }
}

// ---------------- K5: z1 = relu(bn1(y1)) -> padded NHWC bf16 (conv2 input) ----------------
__global__ __launch_bounds__(256) void k_mid(const unsigned short* __restrict__ y1,
                                             const float2* __restrict__ aff,
                                             unsigned short* __restrict__ zp) {
  long idx = (long)blockIdx.x * 256 + threadIdx.x;
  int c0 = (int)(idx & 31) * 8;
  long pos = idx >> 5;
  int b = (int)(pos >> 12), hw = (int)(pos & 4095);
  int h = hw >> 6, w = hw & 63;
  uint4 v = *(const uint4*)(y1 + pos * 256 + c0);
  unsigned vv[4] = {v.x, v.y, v.z, v.w};
  unsigned outp[4];
#pragma unroll
  for (int j = 0; j < 4; ++j) {
    float2 aL = aff[c0 + 2 * j], aH = aff[c0 + 2 * j + 1];
    float lo = fmaxf(aL.x * bf2f((unsigned short)(vv[j] & 0xFFFF)) + aL.y, 0.f);
    float hiv = fmaxf(aH.x * bf2f((unsigned short)(vv[j] >> 16)) + aH.y, 0.f);
    outp[j] = (unsigned)f2bf(lo) | ((unsigned)f2bf(hiv) << 16);
  }
  unsigned short* dst = zp + (long)((b * HP + h + 1) * HP + w + 1) * 256 + c0;
  *(uint4*)dst = make_uint4(outp[0], outp[1], outp[2], outp[3]);
}

// ---------------- K8: out = relu(bn2(y2) + x), NHWC -> NCHW ----------------
__global__ __launch_bounds__(256) void k_final(const unsigned short* __restrict__ y2,
                                               const float2* __restrict__ aff,
                                               const float* __restrict__ x,
                                               float* __restrict__ out) {
  __shared__ float tile[64][33];
  int blk = blockIdx.x;
  int ct = blk & 7, h = (blk >> 3) & 63, b = blk >> 9;
  int c0 = ct * 32;
  int t = threadIdx.x;
  int cl = (t & 15) * 2, w0 = t >> 4;
#pragma unroll
  for (int i = 0; i < 4; ++i) {
    int w = w0 + i * 16;
    unsigned v = *(const unsigned*)(y2 + (long)((b * 4096) + h * 64 + w) * 256 + c0 + cl);
    float2 aL = aff[c0 + cl], aH = aff[c0 + cl + 1];
    tile[w][cl] = aL.x * bf2f((unsigned short)(v & 0xFFFF)) + aL.y;
    tile[w][cl + 1] = aH.x * bf2f((unsigned short)(v >> 16)) + aH.y;
  }
  __syncthreads();
  int w = t & 63, csub = t >> 6;
#pragma unroll
  for (int j = 0; j < 8; ++j) {
    int c = c0 + csub * 8 + j;
    long o = ((long)(b * 256 + c) * 64 + h) * 64 + w;
    out[o] = fmaxf(tile[w][csub * 8 + j] + x[o], 0.f);
  }
}

// ---------------- launch ----------------
extern "C" void kernel_launch(void* const* d_in, const int* in_sizes, int n_in,
                              void* d_out, int out_size, void* d_ws, size_t ws_size,
                              hipStream_t stream) {
  const float* x    = (const float*)d_in[0];
  const float* emb  = (const float*)d_in[1];
  const float* w1   = (const float*)d_in[2];
  const float* w2   = (const float*)d_in[3];
  const float* g1w  = (const float*)d_in[4];
  const float* g1b  = (const float*)d_in[5];
  const float* g2w  = (const float*)d_in[6];
  const float* g2b  = (const float*)d_in[7];
  const float* bn1g = (const float*)d_in[8];
  const float* bn1b = (const float*)d_in[9];
  const float* bn2g = (const float*)d_in[10];
  const float* bn2b = (const float*)d_in[11];

  float* out = (float*)d_out;
  float* gate1 = out + 16777216;
  float* gate2 = gate1 + 4096;

  char* ws = (char*)d_ws;
  const size_t OFF_XP  = 0;                       // 16*66*66*256*2 = 35,684,352
  const size_t OFF_WT1 = 35684352;
  const size_t OFF_WT2 = OFF_WT1 + 1179648;
  const size_t OFF_Y   = OFF_WT2 + 1179648;       // 65536*256*2 = 33,554,432
  const size_t OFF_PART = OFF_Y + 33554432;
  const size_t OFF_AFF1 = OFF_PART + 1048576;
  const size_t OFF_AFF2 = OFF_AFF1 + 2048;

  unsigned short* xp  = (unsigned short*)(ws + OFF_XP);   // x-padded, then z1-padded (k_mid writes interior)
  unsigned short* wT1 = (unsigned short*)(ws + OFF_WT1);
  unsigned short* wT2 = (unsigned short*)(ws + OFF_WT2);
  unsigned short* y   = (unsigned short*)(ws + OFF_Y);
  float* part = (float*)(ws + OFF_PART);
  float2* aff1 = (float2*)(ws + OFF_AFF1);
  float2* aff2 = (float2*)(ws + OFF_AFF2);

  k_prep<<<10816, 256, 0, stream>>>(x, xp, w1, w2, wT1, wT2, emb,
                                    g1w, g1b, g2w, g2b, gate1, gate2);

  k_conv<<<256, 512, 0, stream>>>(xp, wT1, gate1, y, part);
  k_bnfin<<<256, 256, 0, stream>>>(part, bn1g, bn1b, aff1);
  k_mid<<<8192, 256, 0, stream>>>(y, aff1, xp);

  k_conv<<<256, 512, 0, stream>>>(xp, wT2, gate2, y, part);
  k_bnfin<<<256, 256, 0, stream>>>(part, bn2g, bn2b, aff2);
  k_final<<<8192, 256, 0, stream>>>(y, aff2, x, out);
}

// Round 13
// 213.132 us; speedup vs baseline: 1.3745x; 1.1628x over previous
//
#include <hip/hip_runtime.h>

typedef __attribute__((ext_vector_type(8))) short short8;
typedef __attribute__((ext_vector_type(4))) float f32x4;

#define HP 66  // padded spatial dim

__device__ __forceinline__ unsigned short f2bf(float f) {
  unsigned u = __builtin_bit_cast(unsigned, f);
  u += 0x7FFFu + ((u >> 16) & 1u);
  return (unsigned short)(u >> 16);
}
__device__ __forceinline__ float bf2f(unsigned short h) {
  return __builtin_bit_cast(float, ((unsigned)h) << 16);
}
__device__ __forceinline__ __attribute__((address_space(3))) void* to_as3(void* p) {
  return (__attribute__((address_space(3))) void*)(unsigned)(unsigned long long)p;
}
__device__ __forceinline__ const __attribute__((address_space(1))) void* to_as1(const void* p) {
  return (const __attribute__((address_space(1))) void*)(unsigned long long)p;
}

#define SB0() __builtin_amdgcn_sched_barrier(0)
#define BAR() do { SB0(); __builtin_amdgcn_s_barrier(); SB0(); } while (0)

// ---------------- K_prep: convert_x + halo_zero + pack_w + gates in ONE launch ----------------
__global__ __launch_bounds__(256) void k_prep(
    const float* __restrict__ x, unsigned short* __restrict__ xp,
    const float* __restrict__ w1, const float* __restrict__ w2,
    unsigned short* __restrict__ wT1, unsigned short* __restrict__ wT2,
    const float* __restrict__ emb,
    const float* __restrict__ g1w, const float* __restrict__ g1b,
    const float* __restrict__ g2w, const float* __restrict__ g2b,
    float* __restrict__ gate1, float* __restrict__ gate2) {
  __shared__ float tile[32][65];
  __shared__ float ebuf[512];
  __shared__ float red[8];
  const int blk = blockIdx.x;
  const int t = threadIdx.x;

  if (blk < 8192) {
    int ct = blk & 7, h = (blk >> 3) & 63, b = blk >> 9;
    int c0 = ct * 32;
    int w = t & 63, cs = t >> 6;
#pragma unroll
    for (int i = 0; i < 8; ++i) {
      int c = cs + i * 4;
      tile[c][w] = x[(((b * 256) + c0 + c) * 64 + h) * 64 + w];
    }
    __syncthreads();
    int cl = (t & 15) * 2, w0 = t >> 4;
#pragma unroll
    for (int i = 0; i < 4; ++i) {
      int ww = w0 + i * 16;
      unsigned v = (unsigned)f2bf(tile[cl][ww]) | ((unsigned)f2bf(tile[cl + 1][ww]) << 16);
      *(unsigned*)(xp + ((long)((b*HP + h + 1)*HP + (ww + 1)) * 256 + c0 + cl)) = v;
    }
  } else if (blk < 10272) {
    unsigned u = (unsigned)(blk - 8192) * 256 + t;   // < 532480
    unsigned p_idx = u >> 7, word = u & 127;
    int img = p_idx / 260, p = p_idx % 260;
    int h, w;
    if (p < 66)      { h = 0;  w = p; }
    else if (p < 132){ h = 65; w = p - 66; }
    else             { int q = p - 132; h = 1 + (q >> 1); w = (q & 1) * 65; }
    ((unsigned*)xp)[((long)((img*HP + h)*HP + w) * 256) / 2 + word] = 0u;
  } else if (blk < 10784) {
    int idx = blk - 10272;
    const float* w = (idx >> 8) ? w2 : w1;
    unsigned short* wT = (idx >> 8) ? wT2 : wT1;
    int co = idx & 255;
#pragma unroll
    for (int kk = 0; kk < 9; ++kk)
      wT[co * 2304 + kk * 256 + t] = f2bf(w[(co * 256 + t) * 9 + kk]);
  } else {
    int idx = blk - 10784;
    int b = idx & 15;
    const float* gw = (idx >> 4) ? g2w : g1w;
    const float* gbias = (idx >> 4) ? g2b : g1b;
    float* gout = (idx >> 4) ? gate2 : gate1;
    ebuf[t] = emb[b * 512 + t];
    ebuf[t + 256] = emb[b * 512 + t + 256];
    __syncthreads();
    float acc = gbias[t];
    for (int k = 0; k < 512; ++k) acc += ebuf[k] * gw[k * 256 + t];
    float mx = acc;
    for (int off = 32; off >= 1; off >>= 1) mx = fmaxf(mx, __shfl_xor(mx, off));
    if ((t & 63) == 0) red[t >> 6] = mx;
    __syncthreads();
    mx = fmaxf(fmaxf(red[0], red[1]), fmaxf(red[2], red[3]));
    float e = expf(acc - mx);
    float sm = e;
    for (int off = 32; off >= 1; off >>= 1) sm += __shfl_xor(sm, off);
    if ((t & 63) == 0) red[4 + (t >> 6)] = sm;
    __syncthreads();
    sm = red[4] + red[5] + red[6] + red[7];
    gout[b * 256 + t] = e / sm;
  }
}

// ---------------- K3/K6: implicit-GEMM 3x3 conv, 256x256 tile, 8-wave, race-free 2-phase/kt ----------------
// All staging of kt+2 in H2 (after mid-kt barrier) so no LDS region is written in the same
// phase it is read. Stage order per tile {A0,B0,A1,B1}; end-H1 vmcnt(4), end-H2 vmcnt(8).
__global__ __launch_bounds__(512, 2) void k_conv(
    const unsigned short* __restrict__ inp,
    const unsigned short* __restrict__ wT,
    const float* __restrict__ gate,
    unsigned short* __restrict__ yout,
    float* __restrict__ partials) {
  __shared__ short As[2][256][64];   // 64 KB (XOR-swizzled: chunk ^= row&7)
  __shared__ short Bs[2][256][64];   // 64 KB
  __shared__ float sbuf[2][256][2];  // 4 KB epilogue reduce

  const int t = threadIdx.x;
  const int lane = t & 63;
  const int wid = t >> 6;            // 0..7
  const int wm = wid >> 2;           // 0..1  (M half)
  const int wn = wid & 3;            // 0..3  (N quarter)
  const int lr = lane & 15;
  const int hi = lane >> 4;
  const int key = lr & 7;            // read-side swizzle key

  // XCD-aware bijective swizzle: each XCD (8 total) owns 32 consecutive blocks = 2 whole images
  const int blk = ((blockIdx.x & 7) << 5) + (blockIdx.x >> 3);   // 0..255
  const int b = blk >> 4;
  const int hh4 = (blk & 15) << 2;

  // staging geometry: thread stages rows {r0, r0+64} of a 128-row half, 16B chunk
  const int r0 = t >> 3;             // 0..63
  const int cdst = (t & 7) << 3;     // dest element offset (linear LDS)
  const int cg8 = (((t & 7) ^ ((t >> 3) & 7)) << 3);  // pre-swizzled source offset

  int aoff[4];
#pragma unroll
  for (int i = 0; i < 4; ++i)
    aoff[i] = (b * HP + hh4 + i) * HP + r0;

  auto stageA = [&](int buf, int half, int s) {
    int kk = s >> 2;
    int kh = (kk * 11) >> 5;          // kk/3 for kk<=8
    int khw = kh * 66 + (kk - kh * 3);
    int ci = ((s & 3) << 6) + cg8;
    const unsigned short* g0 = inp + (long)(aoff[half * 2 + 0] + khw) * 256 + ci;
    const unsigned short* g1 = inp + (long)(aoff[half * 2 + 1] + khw) * 256 + ci;
    __builtin_amdgcn_global_load_lds(to_as1(g0), to_as3((void*)&As[buf][half * 128 + r0][cdst]), 16, 0, 0);
    __builtin_amdgcn_global_load_lds(to_as1(g1), to_as3((void*)&As[buf][half * 128 + 64 + r0][cdst]), 16, 0, 0);
  };
  auto stageB = [&](int buf, int half, int s) {
    int co0 = half * 128 + r0;
    const unsigned short* g0 = wT + (long)co0 * 2304 + s * 64 + cg8;
    const unsigned short* g1 = wT + (long)(co0 + 64) * 2304 + s * 64 + cg8;
    __builtin_amdgcn_global_load_lds(to_as1(g0), to_as3((void*)&Bs[buf][half * 128 + r0][cdst]), 16, 0, 0);
    __builtin_amdgcn_global_load_lds(to_as1(g1), to_as3((void*)&Bs[buf][half * 128 + 64 + r0][cdst]), 16, 0, 0);
  };

  f32x4 acc[8][4];
#pragma unroll
  for (int i = 0; i < 8; ++i)
#pragma unroll
    for (int j = 0; j < 4; ++j) acc[i][j] = (f32x4){0.f, 0.f, 0.f, 0.f};

  short8 afrag0[4][2], afrag1[4][2];
  short8 bfrag0[2][2], bfrag1[2][2];

#define RD_A(ARR, MH, BUF)                                                           \
  _Pragma("unroll") for (int mf = 0; mf < 4; ++mf)                                   \
    _Pragma("unroll") for (int ks = 0; ks < 2; ++ks)                                 \
      ARR[mf][ks] = *(const short8*)&As[BUF][wm * 128 + ((MH) * 4 + mf) * 16 + lr][((ks * 4 + hi) ^ key) << 3];
#define RD_B(ARR, NH, BUF)                                                           \
  _Pragma("unroll") for (int nf = 0; nf < 2; ++nf)                                   \
    _Pragma("unroll") for (int ks = 0; ks < 2; ++ks)                                 \
      ARR[nf][ks] = *(const short8*)&Bs[BUF][wn * 64 + ((NH) * 2 + nf) * 16 + lr][((ks * 4 + hi) ^ key) << 3];

#define QUADQ(AF, BF, mh, nh)                                                        \
  do {                                                                               \
    __builtin_amdgcn_s_setprio(1);                                                   \
    _Pragma("unroll") for (int ks = 0; ks < 2; ++ks)                                 \
      _Pragma("unroll") for (int mo = 0; mo < 4; ++mo)                               \
        _Pragma("unroll") for (int no = 0; no < 2; ++no)                             \
          acc[(mh) * 4 + mo][(nh) * 2 + no] = __builtin_amdgcn_mfma_f32_16x16x32_bf16( \
              AF[mo][ks], BF[no][ks], acc[(mh) * 4 + mo][(nh) * 2 + no], 0, 0, 0);   \
    __builtin_amdgcn_s_setprio(0);                                                   \
  } while (0)

  // ---- prologue: stage T0,T1 in {A0,B0,A1,B1} order ----
  stageA(0, 0, 0); stageB(0, 0, 0); stageA(0, 1, 0); stageB(0, 1, 0);
  stageA(1, 0, 1); stageB(1, 0, 1); stageA(1, 1, 1); stageB(1, 1, 1);
  asm volatile("s_waitcnt vmcnt(8)" ::: "memory");   // all of tile0 landed
  BAR();
  RD_B(bfrag0, 0, 0);
  RD_A(afrag0, 0, 0);

  // Race-free 2-phase kt body, literal buffer SEL.
  // H1: read B1,A1(kt) from SEL; Q00,Q01,Q10. NO staging (no same-region write window).
  // H2: read A0,B0(kt+1) from SEL^1; stage ALL of kt+2 into SEL (regions' readers all
  //     completed before the mid-kt barrier); Q11.
#define KTHALF2(SEL, kt)                                                             \
  {                                                                                  \
    RD_B(bfrag1, 1, SEL);                                                            \
    RD_A(afrag1, 1, SEL);                                                            \
    SB0();                                                                           \
    QUADQ(afrag0, bfrag0, 0, 0);                                                     \
    QUADQ(afrag0, bfrag1, 0, 1);                                                     \
    QUADQ(afrag1, bfrag0, 1, 0);                                                     \
    if ((kt) < 35) { asm volatile("s_waitcnt vmcnt(4)" ::: "memory"); }              \
    BAR();                                                                           \
    if ((kt) < 35) { RD_B(bfrag0, 0, SEL ^ 1); RD_A(afrag0, 0, SEL ^ 1); }           \
    if ((kt) + 2 < 36) { stageA(SEL, 0, (kt) + 2); stageB(SEL, 0, (kt) + 2);         \
                         stageA(SEL, 1, (kt) + 2); stageB(SEL, 1, (kt) + 2); }       \
    SB0();                                                                           \
    QUADQ(afrag1, bfrag1, 1, 1);                                                     \
    if ((kt) < 34)      { asm volatile("s_waitcnt vmcnt(8)" ::: "memory"); }         \
    else if ((kt) == 34){ asm volatile("s_waitcnt vmcnt(0)" ::: "memory"); }         \
    BAR();                                                                           \
  }

  for (int i = 0; i < 18; ++i) {
    const int kt0 = 2 * i;
    KTHALF2(0, kt0)
    KTHALF2(1, kt0 + 1)
  }
#undef KTHALF2
#undef QUADQ
#undef RD_A
#undef RD_B

  // ---- epilogue (round-8 verified): gate, direct bf16 store, per-channel {sum,sumsq} partials ----
  float g[4];
#pragma unroll
  for (int nf = 0; nf < 4; ++nf) g[nf] = gate[(b << 8) + wn * 64 + nf * 16 + lr];

  float s[4] = {0, 0, 0, 0}, sq[4] = {0, 0, 0, 0};
  const int mrow0 = (blk << 8) + wm * 128 + (hi << 2);
  const int c0 = wn * 64 + lr;
#pragma unroll
  for (int mf = 0; mf < 8; ++mf)
#pragma unroll
    for (int r = 0; r < 4; ++r) {
      const int mm = mrow0 + mf * 16 + r;
#pragma unroll
      for (int nf = 0; nf < 4; ++nf) {
        float v = acc[mf][nf][r] * g[nf];
        yout[(long)mm * 256 + c0 + nf * 16] = f2bf(v);
        s[nf] += v;
        sq[nf] += v * v;
      }
    }
#pragma unroll
  for (int nf = 0; nf < 4; ++nf) {
    s[nf] += __shfl_xor(s[nf], 16);  s[nf] += __shfl_xor(s[nf], 32);
    sq[nf] += __shfl_xor(sq[nf], 16); sq[nf] += __shfl_xor(sq[nf], 32);
  }
  if (hi == 0) {
#pragma unroll
    for (int nf = 0; nf < 4; ++nf) {
      int c = wn * 64 + nf * 16 + lr;
      sbuf[wm][c][0] = s[nf];
      sbuf[wm][c][1] = sq[nf];
    }
  }
  __syncthreads();
  if (t < 256) {
    partials[((blk << 8) + t) * 2]     = sbuf[0][t][0] + sbuf[1][t][0];
    partials[((blk << 8) + t) * 2 + 1] = sbuf[0][t][1] + sbuf[1][t][1];
  }
}

// ---------------- K4/K7: reduce partials -> per-channel BN affine (a, b) ----------------
__global__ __launch_bounds__(256) void k_bnfin(const float* __restrict__ partials,
                                               const float* __restrict__ gamma,
                                               const float* __restrict__ beta,
                                               float2* __restrict__ aff) {
  __shared__ float red[8];
  int c = blockIdx.x, t = threadIdx.x;
  float s = partials[(t * 256 + c) * 2];
  float sq = partials[(t * 256 + c) * 2 + 1];
  for (int off = 32; off >= 1; off >>= 1) { s += __shfl_xor(s, off); sq += __shfl_xor(sq, off); }
  if ((t & 63) == 0) { red[t >> 6] = s; red[4 + (t >> 6)] = sq; }
  __syncthreads();
  if (t == 0) {
    s = red[0] + red[1] + red[2] + red[3];
    sq = red[4] + red[5] + red[6] + red[7];
    float mean = s * (1.0f / 65536.0f);
    float var = fmaxf(sq * (1.0f / 65536.0f) - mean * mean, 0.0f);
    float inv = rsqrtf(var + 1e-5f);
    float ga = gamma[c] * inv;
    aff[c] = make_float2(ga, beta[c] - mean * ga);
  }
}

// ---------------- K5: z1 = relu(bn1(y1)) -> padded NHWC bf16 (conv2 input) ----------------
__global__ __launch_bounds__(256) void k_mid(const unsigned short* __restrict__ y1,
                                             const float2* __restrict__ aff,
                                             unsigned short* __restrict__ zp) {
  long idx = (long)blockIdx.x * 256 + threadIdx.x;
  int c0 = (int)(idx & 31) * 8;
  long pos = idx >> 5;
  int b = (int)(pos >> 12), hw = (int)(pos & 4095);
  int h = hw >> 6, w = hw & 63;
  uint4 v = *(const uint4*)(y1 + pos * 256 + c0);
  unsigned vv[4] = {v.x, v.y, v.z, v.w};
  unsigned outp[4];
#pragma unroll
  for (int j = 0; j < 4; ++j) {
    float2 aL = aff[c0 + 2 * j], aH = aff[c0 + 2 * j + 1];
    float lo = fmaxf(aL.x * bf2f((unsigned short)(vv[j] & 0xFFFF)) + aL.y, 0.f);
    float hiv = fmaxf(aH.x * bf2f((unsigned short)(vv[j] >> 16)) + aH.y, 0.f);
    outp[j] = (unsigned)f2bf(lo) | ((unsigned)f2bf(hiv) << 16);
  }
  unsigned short* dst = zp + (long)((b * HP + h + 1) * HP + w + 1) * 256 + c0;
  *(uint4*)dst = make_uint4(outp[0], outp[1], outp[2], outp[3]);
}

// ---------------- K8: out = relu(bn2(y2) + x), NHWC -> NCHW ----------------
__global__ __launch_bounds__(256) void k_final(const unsigned short* __restrict__ y2,
                                               const float2* __restrict__ aff,
                                               const float* __restrict__ x,
                                               float* __restrict__ out) {
  __shared__ float tile[64][33];
  int blk = blockIdx.x;
  int ct = blk & 7, h = (blk >> 3) & 63, b = blk >> 9;
  int c0 = ct * 32;
  int t = threadIdx.x;
  int cl = (t & 15) * 2, w0 = t >> 4;
#pragma unroll
  for (int i = 0; i < 4; ++i) {
    int w = w0 + i * 16;
    unsigned v = *(const unsigned*)(y2 + (long)((b * 4096) + h * 64 + w) * 256 + c0 + cl);
    float2 aL = aff[c0 + cl], aH = aff[c0 + cl + 1];
    tile[w][cl] = aL.x * bf2f((unsigned short)(v & 0xFFFF)) + aL.y;
    tile[w][cl + 1] = aH.x * bf2f((unsigned short)(v >> 16)) + aH.y;
  }
  __syncthreads();
  int w = t & 63, csub = t >> 6;
#pragma unroll
  for (int j = 0; j < 8; ++j) {
    int c = c0 + csub * 8 + j;
    long o = ((long)(b * 256 + c) * 64 + h) * 64 + w;
    out[o] = fmaxf(tile[w][csub * 8 + j] + x[o], 0.f);
  }
}

// ---------------- launch ----------------
extern "C" void kernel_launch(void* const* d_in, const int* in_sizes, int n_in,
                              void* d_out, int out_size, void* d_ws, size_t ws_size,
                              hipStream_t stream) {
  const float* x    = (const float*)d_in[0];
  const float* emb  = (const float*)d_in[1];
  const float* w1   = (const float*)d_in[2];
  const float* w2   = (const float*)d_in[3];
  const float* g1w  = (const float*)d_in[4];
  const float* g1b  = (const float*)d_in[5];
  const float* g2w  = (const float*)d_in[6];
  const float* g2b  = (const float*)d_in[7];
  const float* bn1g = (const float*)d_in[8];
  const float* bn1b = (const float*)d_in[9];
  const float* bn2g = (const float*)d_in[10];
  const float* bn2b = (const float*)d_in[11];

  float* out = (float*)d_out;
  float* gate1 = out + 16777216;
  float* gate2 = gate1 + 4096;

  char* ws = (char*)d_ws;
  const size_t OFF_XP  = 0;                       // 16*66*66*256*2 = 35,684,352
  const size_t OFF_WT1 = 35684352;
  const size_t OFF_WT2 = OFF_WT1 + 1179648;
  const size_t OFF_Y   = OFF_WT2 + 1179648;       // 65536*256*2 = 33,554,432
  const size_t OFF_PART = OFF_Y + 33554432;
  const size_t OFF_AFF1 = OFF_PART + 1048576;
  const size_t OFF_AFF2 = OFF_AFF1 + 2048;

  unsigned short* xp  = (unsigned short*)(ws + OFF_XP);   // x-padded, then z1-padded (k_mid writes interior)
  unsigned short* wT1 = (unsigned short*)(ws + OFF_WT1);
  unsigned short* wT2 = (unsigned short*)(ws + OFF_WT2);
  unsigned short* y   = (unsigned short*)(ws + OFF_Y);
  float* part = (float*)(ws + OFF_PART);
  float2* aff1 = (float2*)(ws + OFF_AFF1);
  float2* aff2 = (float2*)(ws + OFF_AFF2);

  k_prep<<<10816, 256, 0, stream>>>(x, xp, w1, w2, wT1, wT2, emb,
                                    g1w, g1b, g2w, g2b, gate1, gate2);

  k_conv<<<256, 512, 0, stream>>>(xp, wT1, gate1, y, part);
  k_bnfin<<<256, 256, 0, stream>>>(part, bn1g, bn1b, aff1);
  k_mid<<<8192, 256, 0, stream>>>(y, aff1, xp);

  k_conv<<<256, 512, 0, stream>>>(xp, wT2, gate2, y, part);
  k_bnfin<<<256, 256, 0, stream>>>(part, bn2g, bn2b, aff2);
  k_final<<<8192, 256, 0, stream>>>(y, aff2, x, out);
}